// Round 1
// baseline (59.901 us; speedup 1.0000x reference)
//
#include <hip/hip_runtime.h>

// Reference analysis: softmax over the singleton last axis of `out`
// ([B,N,N,1]) yields exactly 1.0 everywhere (the reference's own comment
// says "yields ones"). mean over B of ones is ones. The adjacency output
// is therefore the constant matrix ones((N,N), float32) — independent of
// x, W1, b1, W2, b2. The optimal kernel is a 1.0f fill of d_out.

__global__ void fill_ones_f4(float4* __restrict__ out, int n4) {
    int i = blockIdx.x * blockDim.x + threadIdx.x;
    if (i < n4) {
        out[i] = make_float4(1.0f, 1.0f, 1.0f, 1.0f);
    }
}

__global__ void fill_ones_tail(float* __restrict__ out, int start, int n) {
    int i = start + blockIdx.x * blockDim.x + threadIdx.x;
    if (i < n) {
        out[i] = 1.0f;
    }
}

extern "C" void kernel_launch(void* const* d_in, const int* in_sizes, int n_in,
                              void* d_out, int out_size, void* d_ws, size_t ws_size,
                              hipStream_t stream) {
    float* out = (float*)d_out;
    int n = out_size;           // expected 256*256 = 65536
    int n4 = n / 4;             // float4 chunks (65536 % 4 == 0)

    if (n4 > 0) {
        int threads = 256;
        int blocks = (n4 + threads - 1) / threads;   // 64 blocks for 16384 float4s
        fill_ones_f4<<<blocks, threads, 0, stream>>>((float4*)out, n4);
    }

    int tail_start = n4 * 4;
    int tail = n - tail_start;
    if (tail > 0) {
        fill_ones_tail<<<1, 64, 0, stream>>>(out, tail_start, n);
    }
}